// Round 1
// baseline (382.017 us; speedup 1.0000x reference)
//
#include <hip/hip_runtime.h>
#include <hip/hip_bf16.h>
#include <stdint.h>

#define T_TOK 4096
#define H_DIM 2048
#define I_DIM 1024
#define E_NUM 8
#define NPAIR 8192          // T_TOK * K_SEL
#define BM 128
#define BK 64
#define MAX_TILES 72        // worst case sum(ceil(M_e/128)) = 71
#define CAP (MAX_TILES * BM) // 9216 padded pair slots

typedef short s16x8 __attribute__((ext_vector_type(8)));
typedef __bf16 bf16x8 __attribute__((ext_vector_type(8)));
typedef float f32x4 __attribute__((ext_vector_type(4)));

using gas1_t = const __attribute__((address_space(1))) void*;
using las3_t = __attribute__((address_space(3))) void*;

__device__ __forceinline__ void async_lds16(const void* g, void* l) {
  // global -> LDS direct copy, 16B/lane; LDS dest = wave-uniform base + lane*16
  __builtin_amdgcn_global_load_lds((gas1_t)(uintptr_t)g,
                                   (las3_t)(uint32_t)(uintptr_t)l, 16, 0, 0);
}

__device__ __forceinline__ unsigned short f2bf(float f) {
  union { float f; unsigned int u; } v; v.f = f;
  unsigned int r = v.u + 0x7FFF + ((v.u >> 16) & 1); // RNE
  return (unsigned short)(r >> 16);
}

__device__ __forceinline__ f32x4 mfma_bf16(s16x8 a, s16x8 b, f32x4 c) {
  return __builtin_amdgcn_mfma_f32_16x16x32_bf16(
      __builtin_bit_cast(bf16x8, a), __builtin_bit_cast(bf16x8, b), c, 0, 0, 0);
}

__device__ __forceinline__ void atom_add_f32(float* p, float v) {
#if defined(__gfx950__) || defined(__gfx942__) || defined(__gfx90a__)
  unsafeAtomicAdd(p, v);   // global_atomic_add_f32 (no CAS loop)
#else
  atomicAdd(p, v);
#endif
}

// ---------------------------------------------------------------- routing ---
__global__ void routing_kernel(const int* __restrict__ sel,
                               const float* __restrict__ rw,
                               int* __restrict__ pair_token,
                               float* __restrict__ pair_weight,
                               int* __restrict__ tile_expert,
                               int* __restrict__ tile_pos) {
  __shared__ int cnt[E_NUM], off[E_NUM], fil[E_NUM];
  const int tid = threadIdx.x;
  if (tid < E_NUM) { cnt[tid] = 0; fil[tid] = 0; }
  __syncthreads();
  for (int p = tid; p < NPAIR; p += blockDim.x) atomicAdd(&cnt[sel[p]], 1);
  // init pads (token 0, weight 0 -> contributes exactly zero)
  for (int q = tid; q < CAP; q += blockDim.x) { pair_token[q] = 0; pair_weight[q] = 0.f; }
  __syncthreads();
  if (tid == 0) {
    int run = 0, idx = 0;
    for (int e = 0; e < E_NUM; ++e) {
      off[e] = run;
      int nt = (cnt[e] + BM - 1) / BM;
      for (int t = 0; t < nt; ++t) { tile_expert[idx] = e; tile_pos[idx] = run + t * BM; ++idx; }
      run += nt * BM;
    }
    for (; idx < MAX_TILES; ++idx) tile_expert[idx] = -1;
  }
  __syncthreads();
  for (int p = tid; p < NPAIR; p += blockDim.x) {
    const int e = sel[p];
    const int pos = off[e] + atomicAdd(&fil[e], 1);
    pair_token[pos] = p >> 1;      // K_SEL == 2
    pair_weight[pos] = rw[p];
  }
}

// ------------------------------------------------------------- elementwise --
__global__ void zero_f32(float4* __restrict__ p, int n4) {
  int i = blockIdx.x * blockDim.x + threadIdx.x;
  const int s = gridDim.x * blockDim.x;
  const float4 z = make_float4(0.f, 0.f, 0.f, 0.f);
  for (; i < n4; i += s) p[i] = z;
}

__global__ void cvt_bf16(const float4* __restrict__ x, ushort4* __restrict__ o, int n4) {
  int i = blockIdx.x * blockDim.x + threadIdx.x;
  const int s = gridDim.x * blockDim.x;
  for (; i < n4; i += s) {
    const float4 v = x[i];
    ushort4 r;
    r.x = f2bf(v.x); r.y = f2bf(v.y); r.z = f2bf(v.z); r.w = f2bf(v.w);
    o[i] = r;
  }
}

// transpose+convert: in fp32 [E][R][C] -> out bf16 [E][C][R]
__global__ void transpose_cvt(const float* __restrict__ in,
                              unsigned short* __restrict__ out, int R, int C) {
  __shared__ float tile[32][33];
  const int e = blockIdx.z;
  const int c0 = blockIdx.x * 32, r0 = blockIdx.y * 32;
  const float* inp = in + (size_t)e * R * C;
  unsigned short* outp = out + (size_t)e * R * C;
  const int tx = threadIdx.x, ty = threadIdx.y;
  tile[ty][tx] = inp[(size_t)(r0 + ty) * C + (c0 + tx)];
  __syncthreads();
  outp[(size_t)(c0 + ty) * R + (r0 + tx)] = f2bf(tile[tx][ty]);
}

// ------------------------------------------------------- GEMM1: gate+up+act --
// A[m][k]  = xb rows gathered by pair_token (M tile = 128 pairs), K = H
// B        = WgT/WuT stored [I][H] so fragments read contiguous along K
// out      = a_pair bf16 [CAP][I]
__launch_bounds__(256, 2)
__global__ void gemm_gate_up(const unsigned short* __restrict__ xb,
                             const unsigned short* __restrict__ WgT,
                             const unsigned short* __restrict__ WuT,
                             const int* __restrict__ pair_token,
                             const int* __restrict__ tile_expert,
                             const int* __restrict__ tile_pos,
                             unsigned short* __restrict__ a_pair) {
  const int mt = blockIdx.x;
  const int e = tile_expert[mt];
  if (e < 0) return;
  const int nt = blockIdx.y;
  const int pbase = tile_pos[mt];
  const int n0 = nt * 128;

  __shared__ unsigned short sA[128 * 64];
  __shared__ unsigned short sBg[128 * 64];
  __shared__ unsigned short sBu[128 * 64];

  const int tid = threadIdx.x;
  const int wid = tid >> 6;
  const int lane = tid & 63;

  const unsigned short* Wg_e = WgT + (size_t)e * (H_DIM * I_DIM);
  const unsigned short* Wu_e = WuT + (size_t)e * (H_DIM * I_DIM);

  // staging sources; LDS layout: row-major [128][64] with 16B-chunk XOR swizzle
  const unsigned short* srcA[4];
  const unsigned short* srcBg[4];
  const unsigned short* srcBu[4];
#pragma unroll
  for (int q = 0; q < 4; ++q) {
    const int row = q * 32 + (tid >> 3);
    const int ch = (tid & 7) ^ (row & 7);   // pre-swizzled global chunk
    const int tok = pair_token[pbase + row];
    srcA[q]  = xb   + (size_t)tok * H_DIM + ch * 8;
    srcBg[q] = Wg_e + (size_t)(n0 + row) * H_DIM + ch * 8;
    srcBu[q] = Wu_e + (size_t)(n0 + row) * H_DIM + ch * 8;
  }

  f32x4 accg[4][4] = {};
  f32x4 accu[4][4] = {};

  const int wm = (wid >> 1) * 64;
  const int wn = (wid & 1) * 64;
  const int fr = lane & 15;
  const int fq = lane >> 4;

  for (int kt = 0; kt < H_DIM / BK; ++kt) {
    const int koff = kt * BK;
#pragma unroll
    for (int q = 0; q < 4; ++q) {
      async_lds16(srcA[q]  + koff, (void*)(sA  + q * 2048 + wid * 512));
      async_lds16(srcBg[q] + koff, (void*)(sBg + q * 2048 + wid * 512));
      async_lds16(srcBu[q] + koff, (void*)(sBu + q * 2048 + wid * 512));
    }
    __syncthreads();   // drains vmcnt -> staged data visible
#pragma unroll
    for (int kk = 0; kk < 2; ++kk) {
      s16x8 aF[4], gF[4], uF[4];
      const int c = kk * 4 + fq;
#pragma unroll
      for (int f = 0; f < 4; ++f) {
        const int ra = wm + f * 16 + fr;
        aF[f] = *(const s16x8*)&sA[ra * 64 + ((c ^ (ra & 7)) * 8)];
        const int rb = wn + f * 16 + fr;
        gF[f] = *(const s16x8*)&sBg[rb * 64 + ((c ^ (rb & 7)) * 8)];
        uF[f] = *(const s16x8*)&sBu[rb * 64 + ((c ^ (rb & 7)) * 8)];
      }
#pragma unroll
      for (int fm = 0; fm < 4; ++fm)
#pragma unroll
        for (int fn = 0; fn < 4; ++fn) {
          accg[fm][fn] = mfma_bf16(aF[fm], gF[fn], accg[fm][fn]);
          accu[fm][fn] = mfma_bf16(aF[fm], uF[fn], accu[fm][fn]);
        }
    }
    __syncthreads();   // guard LDS overwrite by next k-tile
  }

  // epilogue: a = gelu_tanh(g) * u, store bf16
#pragma unroll
  for (int fm = 0; fm < 4; ++fm) {
#pragma unroll
    for (int j = 0; j < 4; ++j) {
      const int prow = pbase + wm + fm * 16 + fq * 4 + j;
      unsigned short* dst = a_pair + (size_t)prow * I_DIM + n0 + wn + fr;
#pragma unroll
      for (int fn = 0; fn < 4; ++fn) {
        const float g = accg[fm][fn][j];
        const float u = accu[fm][fn][j];
        const float t = tanhf(0.7978845608028654f * (g + 0.044715f * g * g * g));
        dst[fn * 16] = f2bf(0.5f * g * (1.0f + t) * u);
      }
    }
  }
}

// ------------------------------------------------------------ GEMM2: down ---
// A = a_pair [CAP][I] (rows contiguous in padded pair space), K = I
// B = WdT [H][I]; epilogue: out[tok] += w * d   (HW fp32 atomics)
__launch_bounds__(256, 2)
__global__ void gemm_down(const unsigned short* __restrict__ a_pair,
                          const unsigned short* __restrict__ WdT,
                          const int* __restrict__ pair_token,
                          const float* __restrict__ pair_weight,
                          const int* __restrict__ tile_expert,
                          const int* __restrict__ tile_pos,
                          float* __restrict__ out) {
  const int mt = blockIdx.x;
  const int e = tile_expert[mt];
  if (e < 0) return;
  const int nt = blockIdx.y;
  const int pbase = tile_pos[mt];
  const int n0 = nt * 128;

  __shared__ unsigned short sA[128 * 64];
  __shared__ unsigned short sB[128 * 64];

  const int tid = threadIdx.x;
  const int wid = tid >> 6;
  const int lane = tid & 63;

  const unsigned short* Wd_e = WdT + (size_t)e * (H_DIM * I_DIM);

  const unsigned short* srcA[4];
  const unsigned short* srcB[4];
#pragma unroll
  for (int q = 0; q < 4; ++q) {
    const int row = q * 32 + (tid >> 3);
    const int ch = (tid & 7) ^ (row & 7);
    srcA[q] = a_pair + (size_t)(pbase + row) * I_DIM + ch * 8;
    srcB[q] = Wd_e + (size_t)(n0 + row) * I_DIM + ch * 8;
  }

  f32x4 acc[4][4] = {};
  const int wm = (wid >> 1) * 64;
  const int wn = (wid & 1) * 64;
  const int fr = lane & 15;
  const int fq = lane >> 4;

  for (int kt = 0; kt < I_DIM / BK; ++kt) {
    const int koff = kt * BK;
#pragma unroll
    for (int q = 0; q < 4; ++q) {
      async_lds16(srcA[q] + koff, (void*)(sA + q * 2048 + wid * 512));
      async_lds16(srcB[q] + koff, (void*)(sB + q * 2048 + wid * 512));
    }
    __syncthreads();
#pragma unroll
    for (int kk = 0; kk < 2; ++kk) {
      s16x8 aF[4], bF[4];
      const int c = kk * 4 + fq;
#pragma unroll
      for (int f = 0; f < 4; ++f) {
        const int ra = wm + f * 16 + fr;
        aF[f] = *(const s16x8*)&sA[ra * 64 + ((c ^ (ra & 7)) * 8)];
        const int rb = wn + f * 16 + fr;
        bF[f] = *(const s16x8*)&sB[rb * 64 + ((c ^ (rb & 7)) * 8)];
      }
#pragma unroll
      for (int fm = 0; fm < 4; ++fm)
#pragma unroll
        for (int fn = 0; fn < 4; ++fn)
          acc[fm][fn] = mfma_bf16(aF[fm], bF[fn], acc[fm][fn]);
    }
    __syncthreads();
  }

#pragma unroll
  for (int fm = 0; fm < 4; ++fm) {
#pragma unroll
    for (int j = 0; j < 4; ++j) {
      const int prow = pbase + wm + fm * 16 + fq * 4 + j;
      const float w = pair_weight[prow];
      if (w == 0.0f) continue;   // padding rows
      const int tok = pair_token[prow];
      float* dst = out + (size_t)tok * H_DIM + n0 + wn + fr;
#pragma unroll
      for (int fn = 0; fn < 4; ++fn)
        atom_add_f32(&dst[fn * 16], w * acc[fm][fn][j]);
    }
  }
}

// ------------------------------------------------------------------ launch --
extern "C" void kernel_launch(void* const* d_in, const int* in_sizes, int n_in,
                              void* d_out, int out_size, void* d_ws, size_t ws_size,
                              hipStream_t stream) {
  const float* x  = (const float*)d_in[0];
  const float* Wg = (const float*)d_in[1];
  const float* Wu = (const float*)d_in[2];
  const float* Wd = (const float*)d_in[3];
  const int*   sel = (const int*)d_in[4];
  const float* rw  = (const float*)d_in[5];
  float* out = (float*)d_out;

  char* ws = (char*)d_ws;
  unsigned short* xb  = (unsigned short*)ws; ws += (size_t)T_TOK * H_DIM * 2;
  unsigned short* WgT = (unsigned short*)ws; ws += (size_t)E_NUM * H_DIM * I_DIM * 2;
  unsigned short* WuT = (unsigned short*)ws; ws += (size_t)E_NUM * H_DIM * I_DIM * 2;
  unsigned short* WdT = (unsigned short*)ws; ws += (size_t)E_NUM * H_DIM * I_DIM * 2;
  unsigned short* a_pair = (unsigned short*)ws; ws += (size_t)CAP * I_DIM * 2;
  int*   pair_token  = (int*)ws;   ws += CAP * 4;
  float* pair_weight = (float*)ws; ws += CAP * 4;
  int*   tile_expert = (int*)ws;   ws += 512;
  int*   tile_pos    = (int*)ws;   ws += 512;

  routing_kernel<<<1, 512, 0, stream>>>(sel, rw, pair_token, pair_weight,
                                        tile_expert, tile_pos);
  zero_f32<<<1024, 256, 0, stream>>>((float4*)out, (T_TOK * H_DIM) / 4);
  cvt_bf16<<<1024, 256, 0, stream>>>((const float4*)x, (ushort4*)xb,
                                     (T_TOK * H_DIM) / 4);
  transpose_cvt<<<dim3(I_DIM / 32, H_DIM / 32, E_NUM), dim3(32, 32), 0, stream>>>(
      Wg, WgT, H_DIM, I_DIM);
  transpose_cvt<<<dim3(I_DIM / 32, H_DIM / 32, E_NUM), dim3(32, 32), 0, stream>>>(
      Wu, WuT, H_DIM, I_DIM);
  transpose_cvt<<<dim3(H_DIM / 32, I_DIM / 32, E_NUM), dim3(32, 32), 0, stream>>>(
      Wd, WdT, I_DIM, H_DIM);

  gemm_gate_up<<<dim3(MAX_TILES, I_DIM / 128), 256, 0, stream>>>(
      xb, WgT, WuT, pair_token, tile_expert, tile_pos, a_pair);
  gemm_down<<<dim3(MAX_TILES, H_DIM / 128), 256, 0, stream>>>(
      a_pair, WdT, pair_token, pair_weight, tile_expert, tile_pos, out);
}

// Round 2
// 337.181 us; speedup vs baseline: 1.1330x; 1.1330x over previous
//
#include <hip/hip_runtime.h>
#include <hip/hip_bf16.h>
#include <stdint.h>

#define T_TOK 4096
#define H_DIM 2048
#define I_DIM 1024
#define E_NUM 8
#define NPAIR 8192           // T_TOK * K_SEL
#define BM 256
#define BK 64
#define MAX_TILES 40         // worst case sum(ceil(M_e/256)) = 39
#define CAP (MAX_TILES * BM) // 10240 padded pair slots

typedef short s16x8 __attribute__((ext_vector_type(8)));
typedef __bf16 bf16x8 __attribute__((ext_vector_type(8)));
typedef float f32x4 __attribute__((ext_vector_type(4)));

using gas1_t = const __attribute__((address_space(1))) void*;
using las3_t = __attribute__((address_space(3))) void*;

__device__ __forceinline__ void async_lds16(const void* g, void* l) {
  __builtin_amdgcn_global_load_lds((gas1_t)(uintptr_t)g,
                                   (las3_t)(uint32_t)(uintptr_t)l, 16, 0, 0);
}

__device__ __forceinline__ unsigned short f2bf(float f) {
  union { float f; unsigned int u; } v; v.f = f;
  unsigned int r = v.u + 0x7FFF + ((v.u >> 16) & 1); // RNE
  return (unsigned short)(r >> 16);
}

__device__ __forceinline__ f32x4 mfma_bf16(s16x8 a, s16x8 b, f32x4 c) {
  return __builtin_amdgcn_mfma_f32_16x16x32_bf16(
      __builtin_bit_cast(bf16x8, a), __builtin_bit_cast(bf16x8, b), c, 0, 0, 0);
}

__device__ __forceinline__ void atom_add_f32(float* p, float v) {
#if defined(__gfx950__) || defined(__gfx942__) || defined(__gfx90a__)
  unsafeAtomicAdd(p, v);
#else
  atomicAdd(p, v);
#endif
}

// ---------------------------------------------------------------- routing ---
__global__ void routing_kernel(const int* __restrict__ sel,
                               const float* __restrict__ rw,
                               int* __restrict__ pair_token,
                               float* __restrict__ pair_weight,
                               int* __restrict__ tile_expert,
                               int* __restrict__ tile_pos) {
  __shared__ int cnt[E_NUM], off[E_NUM], fil[E_NUM];
  const int tid = threadIdx.x;
  if (tid < E_NUM) { cnt[tid] = 0; fil[tid] = 0; }
  __syncthreads();
  for (int p = tid; p < NPAIR; p += blockDim.x) atomicAdd(&cnt[sel[p]], 1);
  for (int q = tid; q < CAP; q += blockDim.x) { pair_token[q] = 0; pair_weight[q] = 0.f; }
  __syncthreads();
  if (tid == 0) {
    int run = 0, idx = 0;
    for (int e = 0; e < E_NUM; ++e) {
      off[e] = run;
      int nt = (cnt[e] + BM - 1) / BM;
      for (int t = 0; t < nt; ++t) { tile_expert[idx] = e; tile_pos[idx] = run + t * BM; ++idx; }
      run += nt * BM;
    }
    for (; idx < MAX_TILES; ++idx) tile_expert[idx] = -1;
  }
  __syncthreads();
  for (int p = tid; p < NPAIR; p += blockDim.x) {
    const int e = sel[p];
    const int pos = off[e] + atomicAdd(&fil[e], 1);
    pair_token[pos] = p >> 1;   // K_SEL == 2
    pair_weight[pos] = rw[p];
  }
}

// ----------------------------------------------- prep: zero out + cvt x -----
__global__ void prep_kernel(const float4* __restrict__ x, ushort4* __restrict__ xb,
                            float4* __restrict__ out, int n4) {
  int i = blockIdx.x * blockDim.x + threadIdx.x;
  const int s = gridDim.x * blockDim.x;
  const float4 z = make_float4(0.f, 0.f, 0.f, 0.f);
  for (; i < n4; i += s) {
    out[i] = z;
    const float4 v = x[i];
    ushort4 r;
    r.x = f2bf(v.x); r.y = f2bf(v.y); r.z = f2bf(v.z); r.w = f2bf(v.w);
    xb[i] = r;
  }
}

// ---------------------------------------- transpose+cvt all three weights ---
// which=0/1: Wg/Wu [2048][1024] -> WguT rows interleaved (gate/up 16-groups),
//            WguT[e][(i>>4)*32 + (i&15) + which*16][h], stride 2048
// which=2  : Wd [1024][2048] -> WdT[e][h][i], stride 1024
__global__ void transpose_all(const float* __restrict__ Wg,
                              const float* __restrict__ Wu,
                              const float* __restrict__ Wd,
                              unsigned short* __restrict__ WguT,
                              unsigned short* __restrict__ WdT) {
  const int z = blockIdx.y;     // 0..23
  const int e = z & 7;
  const int which = z >> 3;
  const int tile = blockIdx.x;  // 512 tiles of 64x64
  int r0, c0, C;
  const float* src;
  if (which < 2) { C = 1024; r0 = (tile >> 4) * 64; c0 = (tile & 15) * 64;
                   src = (which ? Wu : Wg) + (size_t)e * H_DIM * I_DIM; }
  else           { C = 2048; r0 = (tile >> 5) * 64; c0 = (tile & 31) * 64;
                   src = Wd + (size_t)e * H_DIM * I_DIM; }

  __shared__ unsigned short Tl[64][72];
  const int k = threadIdx.x;        // 256 threads
  const int rr = k >> 2;            // 0..63
  const int cb = (k & 3) * 16;      // 0,16,32,48
  const float4* s4 = (const float4*)(src + (size_t)(r0 + rr) * C + c0 + cb);
  unsigned short* dstl = &Tl[rr][cb];
#pragma unroll
  for (int q = 0; q < 4; ++q) {
    const float4 v = s4[q];
    dstl[q * 4 + 0] = f2bf(v.x); dstl[q * 4 + 1] = f2bf(v.y);
    dstl[q * 4 + 2] = f2bf(v.z); dstl[q * 4 + 3] = f2bf(v.w);
  }
  __syncthreads();
  const int oc = k >> 2, rb = (k & 3) * 16;
  union { unsigned short us[16]; uint4 u4[2]; } pk;
#pragma unroll
  for (int i = 0; i < 16; ++i) pk.us[i] = Tl[rb + i][oc];
  const int gc = c0 + oc;
  unsigned short* dst;
  if (which < 2) {
    const int orow = (gc >> 4) * 32 + (gc & 15) + which * 16;
    dst = WguT + ((size_t)e * 2048 + orow) * 2048 + r0 + rb;
  } else {
    dst = WdT + ((size_t)e * 2048 + gc) * 1024 + r0 + rb;
  }
  uint4* d4 = (uint4*)dst;
  d4[0] = pk.u4[0]; d4[1] = pk.u4[1];
}

// ----------------------------------------------------- 8-phase 256^2 GEMM ---
__device__ __forceinline__ void stage2(unsigned short* dst,
                                       const unsigned short* s0,
                                       const unsigned short* s1) {
  async_lds16(s0, dst);
  async_lds16(s1, dst + 4096);  // +8192B: rows 64..127 of the half-tile
}

template<int QM>
__device__ __forceinline__ void lds_a(const unsigned short* shA, int slotA,
                                      int fr, int fq, s16x8 aF[4][2]) {
#pragma unroll
  for (int g = 0; g < 4; ++g)
#pragma unroll
    for (int kk = 0; kk < 2; ++kk) {
      const int ra = QM * 64 + g * 16 + fr;
      aF[g][kk] = *(const s16x8*)&shA[slotA * 8192 + ra * 64 +
                                      (((kk * 4 + fq) ^ (ra & 7)) * 8)];
    }
}

template<int QN>
__device__ __forceinline__ void lds_b(const unsigned short* shB, int slotB,
                                      int wn64, int fr, int fq, s16x8 bF[2][2][2]) {
#pragma unroll
  for (int g = 0; g < 2; ++g)
#pragma unroll
    for (int kk = 0; kk < 2; ++kk) {
      const int rb = wn64 + QN * 32 + g * 16 + fr;
      bF[QN][g][kk] = *(const s16x8*)&shB[slotB * 8192 + rb * 64 +
                                          (((kk * 4 + fq) ^ (rb & 7)) * 8)];
    }
}

template<int QM, int QN>
__device__ __forceinline__ void do_mfma(f32x4 acc[8][4], const s16x8 aF[4][2],
                                        const s16x8 bF[2][2][2]) {
#pragma unroll
  for (int kk = 0; kk < 2; ++kk)
#pragma unroll
    for (int gm = 0; gm < 4; ++gm)
#pragma unroll
      for (int gn = 0; gn < 2; ++gn)
        acc[QM * 4 + gm][QN * 2 + gn] =
            mfma_bf16(aF[gm][kk], bF[QN][gn][kk], acc[QM * 4 + gm][QN * 2 + gn]);
}

// MODE 0: A = xb gathered by pair_token, K=2048, B = WguT -> a_pair (gelu*up)
// MODE 1: A = a_pair, K=1024, B = WdT -> atomic scatter into out
template<int MODE>
__global__ __launch_bounds__(512, 1)
void moe_gemm(const unsigned short* __restrict__ Asrc,
              const unsigned short* __restrict__ Bsrc,
              const int* __restrict__ pair_token,
              const float* __restrict__ pair_weight,
              const int* __restrict__ tile_expert,
              const int* __restrict__ tile_pos,
              unsigned short* __restrict__ a_out,
              float* __restrict__ d_out) {
  constexpr int KD = (MODE == 0) ? H_DIM : I_DIM;
  constexpr int NT = KD / BK;

  const int mt = blockIdx.x;
  const int e = tile_expert[mt];
  if (e < 0) return;
  const int nt = blockIdx.y;
  const int pbase = tile_pos[mt];

  extern __shared__ unsigned short smem[];
  unsigned short* shA = smem;            // 4 slots x [128][64]
  unsigned short* shB = smem + 4 * 8192; // 4 slots x [128][64]

  const int tid = threadIdx.x;
  const int wv = tid >> 6;       // wave 0..7
  const int lane = tid & 63;
  const int fr = lane & 15;
  const int fq = lane >> 4;
  const int wm = (wv >> 2) * 128;          // 0 / 128
  const int wn = (wv & 3) * 64;            // 0/64/128/192
  const int hA = wv >> 2;                  // A half this wave reads
  const int hB = (wv & 3) >> 1;            // B half this wave reads
  const int wn64 = wn & 64;

  // staging source pointers (pre-swizzled chunks)
  const int rbase = wv * 8 + (lane >> 3);          // 0..63
  const int ch = (lane & 7) ^ ((lane >> 3) & 7);
  const unsigned short *srcA00, *srcA01, *srcA10, *srcA11;
  if constexpr (MODE == 0) {
    srcA00 = Asrc + (size_t)pair_token[pbase + rbase] * KD + ch * 8;
    srcA01 = Asrc + (size_t)pair_token[pbase + 64 + rbase] * KD + ch * 8;
    srcA10 = Asrc + (size_t)pair_token[pbase + 128 + rbase] * KD + ch * 8;
    srcA11 = Asrc + (size_t)pair_token[pbase + 192 + rbase] * KD + ch * 8;
  } else {
    srcA00 = Asrc + (size_t)(pbase + rbase) * KD + ch * 8;
    srcA01 = Asrc + (size_t)(pbase + 64 + rbase) * KD + ch * 8;
    srcA10 = Asrc + (size_t)(pbase + 128 + rbase) * KD + ch * 8;
    srcA11 = Asrc + (size_t)(pbase + 192 + rbase) * KD + ch * 8;
  }
  const unsigned short* Be = Bsrc + (size_t)e * 2048 * KD;
  const int nbase = nt * 256 + rbase;
  const unsigned short* srcB00 = Be + (size_t)nbase * KD + ch * 8;
  const unsigned short* srcB01 = Be + (size_t)(nbase + 64) * KD + ch * 8;
  const unsigned short* srcB10 = Be + (size_t)(nbase + 128) * KD + ch * 8;
  const unsigned short* srcB11 = Be + (size_t)(nbase + 192) * KD + ch * 8;

  f32x4 acc[8][4] = {};
  s16x8 aF[4][2];
  s16x8 bF[2][2][2];

  // ---- prologue: A(0,*), B(0,*), B(1,*) ----
  stage2(shA + 0 * 8192 + wv * 512, srcA00, srcA01);
  stage2(shA + 1 * 8192 + wv * 512, srcA10, srcA11);
  stage2(shB + 0 * 8192 + wv * 512, srcB00, srcB01);
  stage2(shB + 1 * 8192 + wv * 512, srcB10, srcB11);
  stage2(shB + 2 * 8192 + wv * 512, srcB00 + BK, srcB01 + BK);
  stage2(shB + 3 * 8192 + wv * 512, srcB10 + BK, srcB11 + BK);
  asm volatile("s_waitcnt vmcnt(4)" ::: "memory");
  __builtin_amdgcn_s_barrier();

  for (int t = 0; t < NT; ++t) {
    const int slotA = (2 * t + hA) & 3;
    const int slotB = (2 * t + hB) & 3;
    // ---- P0: quadrant (0,0); stage A(t+1,0)
    lds_a<0>(shA, slotA, fr, fq, aF);
    lds_b<0>(shB, slotB, wn64, fr, fq, bF);
    if (t + 1 < NT)
      stage2(shA + ((2 * (t + 1)) & 3) * 8192 + wv * 512,
             srcA00 + (size_t)(t + 1) * BK, srcA01 + (size_t)(t + 1) * BK);
    __builtin_amdgcn_s_barrier();
    __builtin_amdgcn_s_setprio(1);
    do_mfma<0, 0>(acc, aF, bF);
    __builtin_amdgcn_s_setprio(0);
    __builtin_amdgcn_s_barrier();
    // ---- P1: quadrant (0,1); stage A(t+1,1)
    lds_b<1>(shB, slotB, wn64, fr, fq, bF);
    if (t + 1 < NT)
      stage2(shA + ((2 * (t + 1) + 1) & 3) * 8192 + wv * 512,
             srcA10 + (size_t)(t + 1) * BK, srcA11 + (size_t)(t + 1) * BK);
    __builtin_amdgcn_s_barrier();
    __builtin_amdgcn_s_setprio(1);
    do_mfma<0, 1>(acc, aF, bF);
    __builtin_amdgcn_s_setprio(0);
    __builtin_amdgcn_s_barrier();
    // ---- P2: quadrant (1,1); stage B(t+2,0)
    lds_a<1>(shA, slotA, fr, fq, aF);
    if (t + 2 < NT)
      stage2(shB + ((2 * (t + 2)) & 3) * 8192 + wv * 512,
             srcB00 + (size_t)(t + 2) * BK, srcB01 + (size_t)(t + 2) * BK);
    __builtin_amdgcn_s_barrier();
    __builtin_amdgcn_s_setprio(1);
    do_mfma<1, 1>(acc, aF, bF);
    __builtin_amdgcn_s_setprio(0);
    __builtin_amdgcn_s_barrier();
    // ---- P3: quadrant (1,0); stage B(t+2,1); counted vmcnt
    if (t + 2 < NT)
      stage2(shB + ((2 * (t + 2) + 1) & 3) * 8192 + wv * 512,
             srcB10 + (size_t)(t + 2) * BK, srcB11 + (size_t)(t + 2) * BK);
    if (t < NT - 2)       asm volatile("s_waitcnt vmcnt(4)" ::: "memory");
    else if (t == NT - 2) asm volatile("s_waitcnt vmcnt(0)" ::: "memory");
    __builtin_amdgcn_s_barrier();
    __builtin_amdgcn_s_setprio(1);
    do_mfma<1, 0>(acc, aF, bF);
    __builtin_amdgcn_s_setprio(0);
    __builtin_amdgcn_s_barrier();
  }

  if constexpr (MODE == 0) {
    // epilogue: col pairs (2q, 2q+1) = (gate, up) for the same output column
    const int colbase = nt * 128 + (wn >> 5) * 16;
#pragma unroll
    for (int am = 0; am < 8; ++am) {
      const int r0e = pbase + wm + am * 16 + fq * 4;
#pragma unroll
      for (int q = 0; q < 2; ++q)
#pragma unroll
        for (int jj = 0; jj < 4; ++jj) {
          const float g = acc[am][2 * q][jj];
          const float u = acc[am][2 * q + 1][jj];
          const float zz = 0.7978845608028654f * (g + 0.044715f * g * g * g);
          const float ex = __expf(2.f * zz);
          const float th = (ex - 1.f) / (ex + 1.f);
          a_out[(size_t)(r0e + jj) * I_DIM + colbase + q * 16 + fr] =
              f2bf(0.5f * g * (1.f + th) * u);
        }
    }
  } else {
#pragma unroll
    for (int am = 0; am < 8; ++am)
#pragma unroll
      for (int jj = 0; jj < 4; ++jj) {
        const int prow = pbase + wm + am * 16 + fq * 4 + jj;
        const float w = pair_weight[prow];
        if (w != 0.f) {
          const int tok = pair_token[prow];
          float* dp = d_out + (size_t)tok * H_DIM + nt * 256 + wn + fr;
#pragma unroll
          for (int an = 0; an < 4; ++an)
            atom_add_f32(dp + an * 16, w * acc[am][an][jj]);
        }
      }
  }
}

// ------------------------------------------------------------------ launch --
extern "C" void kernel_launch(void* const* d_in, const int* in_sizes, int n_in,
                              void* d_out, int out_size, void* d_ws, size_t ws_size,
                              hipStream_t stream) {
  const float* x  = (const float*)d_in[0];
  const float* Wg = (const float*)d_in[1];
  const float* Wu = (const float*)d_in[2];
  const float* Wd = (const float*)d_in[3];
  const int*   sel = (const int*)d_in[4];
  const float* rw  = (const float*)d_in[5];
  float* out = (float*)d_out;

  char* ws = (char*)d_ws;
  unsigned short* xb   = (unsigned short*)ws; ws += (size_t)T_TOK * H_DIM * 2;
  unsigned short* WguT = (unsigned short*)ws; ws += (size_t)E_NUM * 2048 * 2048 * 2;
  unsigned short* WdT  = (unsigned short*)ws; ws += (size_t)E_NUM * H_DIM * I_DIM * 2;
  unsigned short* a_pair = (unsigned short*)ws; ws += (size_t)CAP * I_DIM * 2;
  int*   pair_token  = (int*)ws;   ws += CAP * 4;
  float* pair_weight = (float*)ws; ws += CAP * 4;
  int*   tile_expert = (int*)ws;   ws += 256;
  int*   tile_pos    = (int*)ws;   ws += 256;

  hipFuncSetAttribute((const void*)&moe_gemm<0>,
                      hipFuncAttributeMaxDynamicSharedMemorySize, 131072);
  hipFuncSetAttribute((const void*)&moe_gemm<1>,
                      hipFuncAttributeMaxDynamicSharedMemorySize, 131072);

  routing_kernel<<<1, 512, 0, stream>>>(sel, rw, pair_token, pair_weight,
                                        tile_expert, tile_pos);
  prep_kernel<<<2048, 256, 0, stream>>>((const float4*)x, (ushort4*)xb,
                                        (float4*)out, (T_TOK * H_DIM) / 4);
  transpose_all<<<dim3(512, 24), 256, 0, stream>>>(Wg, Wu, Wd, WguT, WdT);

  moe_gemm<0><<<dim3(MAX_TILES, 8), 512, 131072, stream>>>(
      xb, WguT, pair_token, pair_weight, tile_expert, tile_pos, a_pair, nullptr);
  moe_gemm<1><<<dim3(MAX_TILES, 8), 512, 131072, stream>>>(
      a_pair, WdT, pair_token, pair_weight, tile_expert, tile_pos, nullptr, out);
}